// Round 1
// baseline (27336.105 us; speedup 1.0000x reference)
//
#include <hip/hip_runtime.h>
#include <stdint.h>

#define B_ 16
#define S_ 2048
#define H_ 512
#define M_ (B_ * S_)  // 32768 rows in all big GEMMs

// ---------------------------------------------------------------------------
// GEMM: Y[M,N] = X[M,K] @ W[N,K]^T + b1[N] (+ b2[N]), optional tanh epilogue.
// 128x128 tile, BK=16, 256 threads, 8x8 micro-tile per thread. fp32 VALU.
// ---------------------------------------------------------------------------
template <int ACT>
__global__ __launch_bounds__(256) void gemm_xwt(
    const float* __restrict__ X, const float* __restrict__ W,
    const float* __restrict__ b1, const float* __restrict__ b2,
    float* __restrict__ Y, int K, int ldy)
{
  __shared__ float As[16][132];
  __shared__ float Bs[16][132];
  const int tid = threadIdx.x;
  const int bm = blockIdx.x, bn = blockIdx.y;
  const int ty = tid >> 4, tx = tid & 15;      // 16x16 thread grid
  const int lr = tid >> 2, lk = (tid & 3) << 2; // staging: 64 rows x 4 k-quads
  const float* Xb = X + (size_t)(bm * 128) * K;
  const float* Wb = W + (size_t)(bn * 128) * K;

  float acc[8][8] = {};

  for (int k0 = 0; k0 < K; k0 += 16) {
    float4 xa0 = *(const float4*)(Xb + (size_t)lr * K + k0 + lk);
    float4 xa1 = *(const float4*)(Xb + (size_t)(lr + 64) * K + k0 + lk);
    float4 wa0 = *(const float4*)(Wb + (size_t)lr * K + k0 + lk);
    float4 wa1 = *(const float4*)(Wb + (size_t)(lr + 64) * K + k0 + lk);
    __syncthreads();
    As[lk + 0][lr] = xa0.x; As[lk + 1][lr] = xa0.y; As[lk + 2][lr] = xa0.z; As[lk + 3][lr] = xa0.w;
    As[lk + 0][lr + 64] = xa1.x; As[lk + 1][lr + 64] = xa1.y; As[lk + 2][lr + 64] = xa1.z; As[lk + 3][lr + 64] = xa1.w;
    Bs[lk + 0][lr] = wa0.x; Bs[lk + 1][lr] = wa0.y; Bs[lk + 2][lr] = wa0.z; Bs[lk + 3][lr] = wa0.w;
    Bs[lk + 0][lr + 64] = wa1.x; Bs[lk + 1][lr + 64] = wa1.y; Bs[lk + 2][lr + 64] = wa1.z; Bs[lk + 3][lr + 64] = wa1.w;
    __syncthreads();
#pragma unroll
    for (int kk = 0; kk < 16; ++kk) {
      float4 a0 = *(const float4*)&As[kk][ty * 8];
      float4 a1 = *(const float4*)&As[kk][ty * 8 + 4];
      float4 b0 = *(const float4*)&Bs[kk][tx * 8];
      float4 b1v = *(const float4*)&Bs[kk][tx * 8 + 4];
      float av[8] = {a0.x, a0.y, a0.z, a0.w, a1.x, a1.y, a1.z, a1.w};
      float bv[8] = {b0.x, b0.y, b0.z, b0.w, b1v.x, b1v.y, b1v.z, b1v.w};
#pragma unroll
      for (int i = 0; i < 8; ++i)
#pragma unroll
        for (int j = 0; j < 8; ++j) acc[i][j] += av[i] * bv[j];
    }
  }

  const int ncol0 = bn * 128 + tx * 8;
  float bias[8];
#pragma unroll
  for (int j = 0; j < 8; ++j) {
    float bb = b1[ncol0 + j];
    if (b2) bb += b2[ncol0 + j];
    bias[j] = bb;
  }
#pragma unroll
  for (int i = 0; i < 8; ++i) {
    size_t row = (size_t)bm * 128 + ty * 8 + i;
    float* yp = Y + row * (size_t)ldy + ncol0;
    float out[8];
#pragma unroll
    for (int j = 0; j < 8; ++j) {
      float v = acc[i][j] + bias[j];
      if (ACT) v = tanhf(v);
      out[j] = v;
    }
    *(float4*)(yp)     = make_float4(out[0], out[1], out[2], out[3]);
    *(float4*)(yp + 4) = make_float4(out[4], out[5], out[6], out[7]);
  }
}

// ---------------------------------------------------------------------------
// Attention fusion: per row, scores = <a,ctx>,<v,ctx>,<l,ctx>; softmax3;
// fusion = wa*a + wv*v + wl*l.  One wave (64 lanes) per row, 4 rows/block.
// ---------------------------------------------------------------------------
__global__ __launch_bounds__(256) void fusion_kernel(
    const float* __restrict__ F,    // [M, 1536] = a|v|l
    const float* __restrict__ CTX,  // [M, 512]
    float* __restrict__ FU)         // [M, 512]
{
  const int row = blockIdx.x * 4 + (threadIdx.x >> 6);
  const int lane = threadIdx.x & 63;
  const float* a = F + (size_t)row * 1536;
  const float* v = a + 512;
  const float* l = a + 1024;
  const float* c = CTX + (size_t)row * 512;
  float sa = 0.f, sv = 0.f, sl = 0.f;
  for (int k = lane; k < 512; k += 64) {
    float cv = c[k];
    sa += a[k] * cv; sv += v[k] * cv; sl += l[k] * cv;
  }
#pragma unroll
  for (int off = 1; off < 64; off <<= 1) {
    sa += __shfl_xor(sa, off);
    sv += __shfl_xor(sv, off);
    sl += __shfl_xor(sl, off);
  }
  float m = fmaxf(sa, fmaxf(sv, sl));
  float ea = expf(sa - m), ev = expf(sv - m), el = expf(sl - m);
  float inv = 1.0f / (ea + ev + el);
  float wa = ea * inv, wv = ev * inv, wl = el * inv;
  float* fu = FU + (size_t)row * 512;
  for (int k = lane; k < 512; k += 64)
    fu[k] = wa * a[k] + wv * v[k] + wl * l[k];
}

// ---------------------------------------------------------------------------
// Persistent LSTM. 16 WGs per batch (256 total, 1/CU). Each WG owns 32 hidden
// units (=128 gate rows of Whh held in VGPRs: 256 fp32/thread @ 1 wave/SIMD).
// Per step: stage h (2KB) to LDS, 256 FMAs/thread, pair-reduce, pointwise,
// publish h slice to global ring, per-batch 16-WG flag barrier (agent scope).
// XCD swizzle: batch = 2*(bi%8) + (bi/8)%2 puts each batch's 16 WGs on one
// XCD under the %8 round-robin heuristic (correctness does not depend on it).
// ---------------------------------------------------------------------------
__global__ __launch_bounds__(256, 1) void lstm_kernel(
    const float* __restrict__ G,    // [B*S, 2048] precomputed x@Wih.T + biases
    const float* __restrict__ Whh,  // [2048, 512]
    const float* __restrict__ h0,   // [B, 512]
    const float* __restrict__ c0,   // [B, 512]
    float* __restrict__ ring,       // [2][B][512]
    unsigned int* __restrict__ arr, // [B][S] arrival counters (pre-zeroed)
    float* __restrict__ r_out,      // [B, S, 512]
    float* __restrict__ hT,         // [B, 512]
    float* __restrict__ cT)         // [B, 512]
{
  const int bi = blockIdx.x;
  const int b  = ((bi & 7) << 1) | ((bi >> 3) & 1);
  const int wg = bi >> 4;
  const int k0h = wg << 5;  // hidden-slice base (32 units)
  const int tid = threadIdx.x;

  __shared__ float h_lds[512];
  __shared__ float gates_lds[128];
  __shared__ float c_lds[32];

  const int col = tid >> 1;       // 0..127 local gate row
  const int khalf = tid & 1;      // k-half of the 512-dot
  const int kbase = khalf << 8;   // 0 or 256
  const int g = col >> 5, ul = col & 31;
  const int gcol = g * 512 + k0h + ul;  // row in Whh == column in G

  // Whh slice into registers (one-time, ~64 MB total HBM)
  float4 warr[64];
  const float* wsrc = Whh + (size_t)gcol * 512 + kbase;
#pragma unroll
  for (int j = 0; j < 64; ++j) warr[j] = *(const float4*)(wsrc + j * 4);

  if (tid < 32) c_lds[tid] = c0[b * H_ + k0h + tid];
  __syncthreads();

  unsigned int* arrb = arr + b * S_;
  const float* gbase = G + (size_t)b * S_ * 2048;

  for (int t = 0; t < S_; ++t) {
    // prefetch this step's G value; overlaps the spin-wait below
    float gval = 0.f;
    if (khalf == 0) gval = gbase[(size_t)t * 2048 + gcol];

    if (t > 0) {
      if (tid == 0) {
        while (__hip_atomic_load(&arrb[t - 1], __ATOMIC_RELAXED,
                                 __HIP_MEMORY_SCOPE_AGENT) < 16u)
          __builtin_amdgcn_s_sleep(1);
        (void)__hip_atomic_load(&arrb[t - 1], __ATOMIC_ACQUIRE,
                                __HIP_MEMORY_SCOPE_AGENT);
      }
      __syncthreads();
      const float* hsrc = ring + ((size_t)(t & 1) * B_ + b) * H_;
      h_lds[tid]       = __hip_atomic_load(hsrc + tid,       __ATOMIC_RELAXED, __HIP_MEMORY_SCOPE_AGENT);
      h_lds[tid + 256] = __hip_atomic_load(hsrc + tid + 256, __ATOMIC_RELAXED, __HIP_MEMORY_SCOPE_AGENT);
    } else {
      const float* hsrc = h0 + b * H_;
      h_lds[tid] = hsrc[tid];
      h_lds[tid + 256] = hsrc[tid + 256];
    }
    __syncthreads();

    float4 s4 = make_float4(0.f, 0.f, 0.f, 0.f);
#pragma unroll
    for (int j = 0; j < 64; ++j) {
      float4 hv = *(const float4*)&h_lds[kbase + (j << 2)];
      s4.x += warr[j].x * hv.x;
      s4.y += warr[j].y * hv.y;
      s4.z += warr[j].z * hv.z;
      s4.w += warr[j].w * hv.w;
    }
    float sum = (s4.x + s4.y) + (s4.z + s4.w);
    sum += __shfl_xor(sum, 1);
    if (khalf == 0) gates_lds[col] = sum + gval;
    __syncthreads();

    if (tid < 32) {
      const int u = tid;
      float ip = gates_lds[u], fp = gates_lds[32 + u];
      float gp = gates_lds[64 + u], op = gates_lds[96 + u];
      float ig = 1.f / (1.f + expf(-ip));
      float fg = 1.f / (1.f + expf(-fp));
      float gg = tanhf(gp);
      float og = 1.f / (1.f + expf(-op));
      float cn = fg * c_lds[u] + ig * gg;
      c_lds[u] = cn;
      float hn = og * tanhf(cn);
      __hip_atomic_store(ring + ((size_t)((t + 1) & 1) * B_ + b) * H_ + k0h + u,
                         hn, __ATOMIC_RELAXED, __HIP_MEMORY_SCOPE_AGENT);
      r_out[((size_t)b * S_ + t) * H_ + k0h + u] = hn;
      if (t == S_ - 1) {
        hT[b * H_ + k0h + u] = hn;
        cT[b * H_ + k0h + u] = cn;
      }
    }
    __syncthreads();
    if (tid == 0) {
      __threadfence();
      __hip_atomic_fetch_add(&arrb[t], 1u, __ATOMIC_RELEASE,
                             __HIP_MEMORY_SCOPE_AGENT);
    }
  }
}

// ---------------------------------------------------------------------------
// ws layout (bytes):
//   [0, 256MB)        : F [32768,1536] fp32 (a|v|l), later reused as G [32768,2048]
//   [256MB, 320MB)    : CTX [32768,512]
//   [320MB, 384MB)    : FU  [32768,512]
//   [384MB, +64KB)    : h ring [2][16][512]
//   [.., +128KB)      : arrival counters [16][2048]
// Total ≈ 385 MB.
// ---------------------------------------------------------------------------
extern "C" void kernel_launch(void* const* d_in, const int* in_sizes, int n_in,
                              void* d_out, int out_size, void* d_ws, size_t ws_size,
                              hipStream_t stream)
{
  const float* a_in = (const float*)d_in[0];
  const float* v_in = (const float*)d_in[1];
  const float* l_in = (const float*)d_in[2];
  const float* h0   = (const float*)d_in[3];
  const float* c0   = (const float*)d_in[4];
  const float* Wa = (const float*)d_in[5];   const float* ba = (const float*)d_in[6];
  const float* Wv = (const float*)d_in[7];   const float* bv = (const float*)d_in[8];
  const float* Wl = (const float*)d_in[9];   const float* bl = (const float*)d_in[10];
  const float* Wc = (const float*)d_in[11];  const float* bc = (const float*)d_in[12];
  const float* Wih = (const float*)d_in[13]; const float* Whh = (const float*)d_in[14];
  const float* bih = (const float*)d_in[15]; const float* bhh = (const float*)d_in[16];

  char* ws = (char*)d_ws;
  float* Fbuf = (float*)ws;                       // also Gbuf after fusion
  float* Gbuf = (float*)ws;
  float* CTX  = (float*)(ws + 268435456ull);
  float* FU   = (float*)(ws + 335544320ull);
  float* ringp = (float*)(ws + 402653184ull);
  unsigned int* arrp = (unsigned int*)(ws + 402653184ull + 65536ull);

  dim3 blk(256);
  // projections into F (ld 1536): a|v|l
  gemm_xwt<0><<<dim3(256, 4), blk, 0, stream>>>(a_in, Wa, ba, nullptr, Fbuf + 0,    512,  1536);
  gemm_xwt<0><<<dim3(256, 4), blk, 0, stream>>>(v_in, Wv, bv, nullptr, Fbuf + 512,  768,  1536);
  gemm_xwt<0><<<dim3(256, 4), blk, 0, stream>>>(l_in, Wl, bl, nullptr, Fbuf + 1024, 1024, 1536);
  // context = tanh(F @ Wc^T + bc)
  gemm_xwt<1><<<dim3(256, 4), blk, 0, stream>>>(Fbuf, Wc, bc, nullptr, CTX, 1536, 512);
  // softmax-weighted fusion
  fusion_kernel<<<dim3(8192), blk, 0, stream>>>(Fbuf, CTX, FU);
  // G = FU @ Wih^T + bih + bhh   (overwrites F region — F is dead)
  gemm_xwt<0><<<dim3(256, 16), blk, 0, stream>>>(FU, Wih, bih, bhh, Gbuf, 512, 2048);
  // zero arrival counters, then the persistent sequential LSTM
  hipMemsetAsync(arrp, 0, (size_t)B_ * S_ * sizeof(unsigned int), stream);
  float* out = (float*)d_out;
  lstm_kernel<<<dim3(256), blk, 0, stream>>>(Gbuf, Whh, h0, c0, ringp, arrp,
                                             out, out + 16777216ull,
                                             out + 16777216ull + 8192ull);
}

// Round 2
// 10922.923 us; speedup vs baseline: 2.5026x; 2.5026x over previous
//
#include <hip/hip_runtime.h>
#include <stdint.h>

#define B_ 16
#define S_ 2048
#define H_ 512
#define M_ (B_ * S_)  // 32768 rows in all big GEMMs

// ---------------------------------------------------------------------------
// GEMM: Y[M,N] = X[M,K] @ W[N,K]^T + b1[N] (+ b2[N]), optional tanh epilogue.
// 128x128 tile, BK=16, 256 threads, 8x8 micro-tile per thread. fp32 VALU.
// (unchanged from R1 — next round's target)
// ---------------------------------------------------------------------------
template <int ACT>
__global__ __launch_bounds__(256) void gemm_xwt(
    const float* __restrict__ X, const float* __restrict__ W,
    const float* __restrict__ b1, const float* __restrict__ b2,
    float* __restrict__ Y, int K, int ldy)
{
  __shared__ float As[16][132];
  __shared__ float Bs[16][132];
  const int tid = threadIdx.x;
  const int bm = blockIdx.x, bn = blockIdx.y;
  const int ty = tid >> 4, tx = tid & 15;      // 16x16 thread grid
  const int lr = tid >> 2, lk = (tid & 3) << 2; // staging: 64 rows x 4 k-quads
  const float* Xb = X + (size_t)(bm * 128) * K;
  const float* Wb = W + (size_t)(bn * 128) * K;

  float acc[8][8] = {};

  for (int k0 = 0; k0 < K; k0 += 16) {
    float4 xa0 = *(const float4*)(Xb + (size_t)lr * K + k0 + lk);
    float4 xa1 = *(const float4*)(Xb + (size_t)(lr + 64) * K + k0 + lk);
    float4 wa0 = *(const float4*)(Wb + (size_t)lr * K + k0 + lk);
    float4 wa1 = *(const float4*)(Wb + (size_t)(lr + 64) * K + k0 + lk);
    __syncthreads();
    As[lk + 0][lr] = xa0.x; As[lk + 1][lr] = xa0.y; As[lk + 2][lr] = xa0.z; As[lk + 3][lr] = xa0.w;
    As[lk + 0][lr + 64] = xa1.x; As[lk + 1][lr + 64] = xa1.y; As[lk + 2][lr + 64] = xa1.z; As[lk + 3][lr + 64] = xa1.w;
    Bs[lk + 0][lr] = wa0.x; Bs[lk + 1][lr] = wa0.y; Bs[lk + 2][lr] = wa0.z; Bs[lk + 3][lr] = wa0.w;
    Bs[lk + 0][lr + 64] = wa1.x; Bs[lk + 1][lr + 64] = wa1.y; Bs[lk + 2][lr + 64] = wa1.z; Bs[lk + 3][lr + 64] = wa1.w;
    __syncthreads();
#pragma unroll
    for (int kk = 0; kk < 16; ++kk) {
      float4 a0 = *(const float4*)&As[kk][ty * 8];
      float4 a1 = *(const float4*)&As[kk][ty * 8 + 4];
      float4 b0 = *(const float4*)&Bs[kk][tx * 8];
      float4 b1v = *(const float4*)&Bs[kk][tx * 8 + 4];
      float av[8] = {a0.x, a0.y, a0.z, a0.w, a1.x, a1.y, a1.z, a1.w};
      float bv[8] = {b0.x, b0.y, b0.z, b0.w, b1v.x, b1v.y, b1v.z, b1v.w};
#pragma unroll
      for (int i = 0; i < 8; ++i)
#pragma unroll
        for (int j = 0; j < 8; ++j) acc[i][j] += av[i] * bv[j];
    }
  }

  const int ncol0 = bn * 128 + tx * 8;
  float bias[8];
#pragma unroll
  for (int j = 0; j < 8; ++j) {
    float bb = b1[ncol0 + j];
    if (b2) bb += b2[ncol0 + j];
    bias[j] = bb;
  }
#pragma unroll
  for (int i = 0; i < 8; ++i) {
    size_t row = (size_t)bm * 128 + ty * 8 + i;
    float* yp = Y + row * (size_t)ldy + ncol0;
    float out[8];
#pragma unroll
    for (int j = 0; j < 8; ++j) {
      float v = acc[i][j] + bias[j];
      if (ACT) v = tanhf(v);
      out[j] = v;
    }
    *(float4*)(yp)     = make_float4(out[0], out[1], out[2], out[3]);
    *(float4*)(yp + 4) = make_float4(out[4], out[5], out[6], out[7]);
  }
}

// ---------------------------------------------------------------------------
// Attention fusion (unchanged).
// ---------------------------------------------------------------------------
__global__ __launch_bounds__(256) void fusion_kernel(
    const float* __restrict__ F,    // [M, 1536] = a|v|l
    const float* __restrict__ CTX,  // [M, 512]
    float* __restrict__ FU)         // [M, 512]
{
  const int row = blockIdx.x * 4 + (threadIdx.x >> 6);
  const int lane = threadIdx.x & 63;
  const float* a = F + (size_t)row * 1536;
  const float* v = a + 512;
  const float* l = a + 1024;
  const float* c = CTX + (size_t)row * 512;
  float sa = 0.f, sv = 0.f, sl = 0.f;
  for (int k = lane; k < 512; k += 64) {
    float cv = c[k];
    sa += a[k] * cv; sv += v[k] * cv; sl += l[k] * cv;
  }
#pragma unroll
  for (int off = 1; off < 64; off <<= 1) {
    sa += __shfl_xor(sa, off);
    sv += __shfl_xor(sv, off);
    sl += __shfl_xor(sl, off);
  }
  float m = fmaxf(sa, fmaxf(sv, sl));
  float ea = expf(sa - m), ev = expf(sv - m), el = expf(sl - m);
  float inv = 1.0f / (ea + ev + el);
  float wa = ea * inv, wv = ev * inv, wl = el * inv;
  float* fu = FU + (size_t)row * 512;
  for (int k = lane; k < 512; k += 64)
    fu[k] = wa * a[k] + wv * v[k] + wl * l[k];
}

// ---------------------------------------------------------------------------
// Persistent LSTM with TAG-IN-WORD sync (no fences, no counters, no s_sleep).
// h element published as one relaxed 64-bit atomic: (tag=t)<<32 | bits(h).
// Payload travels with the flag -> single L2 round trip producer->consumer.
// Ring depth 4; WG skew within a batch is <=1 step (every h needs all 16
// slices), so tags can never lap. 0xAA poison never matches a tag in [0,2048).
// 16 WGs per batch (256 total, 1/CU); each WG owns 32 hidden units
// (128 gate rows of Whh in VGPRs/AGPRs). XCD swizzle groups a batch's 16 WGs
// on one XCD under the %8 round-robin heuristic (perf-only, not correctness).
// ---------------------------------------------------------------------------
__global__ __launch_bounds__(256, 1) void lstm_kernel(
    const float* __restrict__ G,    // [B*S, 2048] precomputed x@Wih.T + biases
    const float* __restrict__ Whh,  // [2048, 512]
    const float* __restrict__ h0,   // [B, 512]
    const float* __restrict__ c0,   // [B, 512]
    unsigned long long* __restrict__ ring,  // [4][B][512] tagged h words
    float* __restrict__ r_out,      // [B, S, 512]
    float* __restrict__ hT,         // [B, 512]
    float* __restrict__ cT)         // [B, 512]
{
  const int bi = blockIdx.x;
  const int b  = ((bi & 7) << 1) | ((bi >> 3) & 1);
  const int wg = bi >> 4;
  const int k0h = wg << 5;  // hidden-slice base (32 units)
  const int tid = threadIdx.x;

  __shared__ float h_lds[512];
  __shared__ float gates_lds[128];
  __shared__ float c_lds[32];

  const int col = tid >> 1;       // 0..127 local gate row
  const int khalf = tid & 1;      // k-half of the 512-dot
  const int kbase = khalf << 8;   // 0 or 256
  const int g = col >> 5, ul = col & 31;
  const int gcol = g * 512 + k0h + ul;  // row in Whh == column in G

  // Whh slice into registers (one-time)
  float4 warr[64];
  const float* wsrc = Whh + (size_t)gcol * 512 + kbase;
#pragma unroll
  for (int j = 0; j < 64; ++j) warr[j] = *(const float4*)(wsrc + j * 4);

  if (tid < 32) c_lds[tid] = c0[b * H_ + k0h + tid];
  __syncthreads();

  const float* gbase = G + (size_t)b * S_ * 2048;

  for (int t = 0; t < S_; ++t) {
    // prefetch this step's G value; overlaps the spin below
    float gval = 0.f;
    if (khalf == 0) gval = gbase[(size_t)t * 2048 + gcol];

    if (t > 0) {
      const unsigned int want = (unsigned int)(t - 1);
      const unsigned long long* slot =
          ring + ((size_t)((t - 1) & 3) * B_ + b) * H_;
      unsigned long long v0, v1;
      do {
        v0 = __hip_atomic_load(slot + tid, __ATOMIC_RELAXED,
                               __HIP_MEMORY_SCOPE_AGENT);
      } while ((unsigned int)(v0 >> 32) != want);
      do {
        v1 = __hip_atomic_load(slot + tid + 256, __ATOMIC_RELAXED,
                               __HIP_MEMORY_SCOPE_AGENT);
      } while ((unsigned int)(v1 >> 32) != want);
      h_lds[tid]       = __builtin_bit_cast(float, (unsigned int)v0);
      h_lds[tid + 256] = __builtin_bit_cast(float, (unsigned int)v1);
    } else {
      const float* hsrc = h0 + b * H_;
      h_lds[tid] = hsrc[tid];
      h_lds[tid + 256] = hsrc[tid + 256];
    }
    __syncthreads();

    float4 s4 = make_float4(0.f, 0.f, 0.f, 0.f);
#pragma unroll
    for (int j = 0; j < 64; ++j) {
      float4 hv = *(const float4*)&h_lds[kbase + (j << 2)];
      s4.x += warr[j].x * hv.x;
      s4.y += warr[j].y * hv.y;
      s4.z += warr[j].z * hv.z;
      s4.w += warr[j].w * hv.w;
    }
    float sum = (s4.x + s4.y) + (s4.z + s4.w);
    sum += __shfl_xor(sum, 1);
    if (khalf == 0) gates_lds[col] = sum + gval;
    __syncthreads();

    if (tid < 32) {
      const int u = tid;
      float ip = gates_lds[u], fp = gates_lds[32 + u];
      float gp = gates_lds[64 + u], op = gates_lds[96 + u];
      float ig = 1.f / (1.f + expf(-ip));
      float fg = 1.f / (1.f + expf(-fp));
      float gg = tanhf(gp);
      float og = 1.f / (1.f + expf(-op));
      float cn = fg * c_lds[u] + ig * gg;
      c_lds[u] = cn;
      float hn = og * tanhf(cn);
      unsigned long long pk =
          ((unsigned long long)(unsigned int)t << 32) |
          (unsigned long long)__builtin_bit_cast(unsigned int, hn);
      __hip_atomic_store(ring + ((size_t)(t & 3) * B_ + b) * H_ + k0h + u,
                         pk, __ATOMIC_RELAXED, __HIP_MEMORY_SCOPE_AGENT);
      r_out[((size_t)b * S_ + t) * H_ + k0h + u] = hn;
      if (t == S_ - 1) {
        hT[b * H_ + k0h + u] = hn;
        cT[b * H_ + k0h + u] = cn;
      }
    }
    __syncthreads();
  }
}

// ---------------------------------------------------------------------------
// ws layout (bytes):
//   [0, 256MB)        : F [32768,1536] fp32 (a|v|l), later reused as G [32768,2048]
//   [256MB, 320MB)    : CTX [32768,512]
//   [320MB, 384MB)    : FU  [32768,512]
//   [384MB, +256KB)   : tagged h ring [4][16][512] x u64
// Total ≈ 385 MB.
// ---------------------------------------------------------------------------
extern "C" void kernel_launch(void* const* d_in, const int* in_sizes, int n_in,
                              void* d_out, int out_size, void* d_ws, size_t ws_size,
                              hipStream_t stream)
{
  const float* a_in = (const float*)d_in[0];
  const float* v_in = (const float*)d_in[1];
  const float* l_in = (const float*)d_in[2];
  const float* h0   = (const float*)d_in[3];
  const float* c0   = (const float*)d_in[4];
  const float* Wa = (const float*)d_in[5];   const float* ba = (const float*)d_in[6];
  const float* Wv = (const float*)d_in[7];   const float* bv = (const float*)d_in[8];
  const float* Wl = (const float*)d_in[9];   const float* bl = (const float*)d_in[10];
  const float* Wc = (const float*)d_in[11];  const float* bc = (const float*)d_in[12];
  const float* Wih = (const float*)d_in[13]; const float* Whh = (const float*)d_in[14];
  const float* bih = (const float*)d_in[15]; const float* bhh = (const float*)d_in[16];

  char* ws = (char*)d_ws;
  float* Fbuf = (float*)ws;                       // also Gbuf after fusion
  float* Gbuf = (float*)ws;
  float* CTX  = (float*)(ws + 268435456ull);
  float* FU   = (float*)(ws + 335544320ull);
  unsigned long long* ringp = (unsigned long long*)(ws + 402653184ull);

  dim3 blk(256);
  // projections into F (ld 1536): a|v|l
  gemm_xwt<0><<<dim3(256, 4), blk, 0, stream>>>(a_in, Wa, ba, nullptr, Fbuf + 0,    512,  1536);
  gemm_xwt<0><<<dim3(256, 4), blk, 0, stream>>>(v_in, Wv, bv, nullptr, Fbuf + 512,  768,  1536);
  gemm_xwt<0><<<dim3(256, 4), blk, 0, stream>>>(l_in, Wl, bl, nullptr, Fbuf + 1024, 1024, 1536);
  // context = tanh(F @ Wc^T + bc)
  gemm_xwt<1><<<dim3(256, 4), blk, 0, stream>>>(Fbuf, Wc, bc, nullptr, CTX, 1536, 512);
  // softmax-weighted fusion
  fusion_kernel<<<dim3(8192), blk, 0, stream>>>(Fbuf, CTX, FU);
  // G = FU @ Wih^T + bih + bhh   (overwrites F region — F is dead)
  gemm_xwt<0><<<dim3(256, 16), blk, 0, stream>>>(FU, Wih, bih, bhh, Gbuf, 512, 2048);
  // persistent sequential LSTM (tag-in-word sync; no memset needed)
  float* out = (float*)d_out;
  lstm_kernel<<<dim3(256), blk, 0, stream>>>(Gbuf, Whh, h0, c0, ringp,
                                             out, out + 16777216ull,
                                             out + 16777216ull + 8192ull);
}